// Round 16
// baseline (349.935 us; speedup 1.0000x reference)
//
#include <hip/hip_runtime.h>
#include <math.h>

typedef short bf16x8 __attribute__((ext_vector_type(8)));
typedef float f32x4  __attribute__((ext_vector_type(4)));

#define GLOAD_LDS16(SRC, DST) \
  __builtin_amdgcn_global_load_lds((const __attribute__((address_space(1))) void*)(SRC), \
      (__attribute__((address_space(3))) void*)(DST), 16, 0, 0)

#define WAITVM(N) asm volatile("s_waitcnt vmcnt(" #N ")" ::: "memory")
#define WAITLGKM0 asm volatile("s_waitcnt lgkmcnt(0)" ::: "memory")
#define BARRIER() do { __builtin_amdgcn_s_barrier(); asm volatile("" ::: "memory"); } while (0)

__device__ __forceinline__ unsigned short f2bf(float f) {
  union { float f; unsigned u; } v; v.f = f;
  unsigned r = v.u + 0x7FFFu + ((v.u >> 16) & 1u);   // RNE
  return (unsigned short)(r >> 16);
}
__device__ __forceinline__ float bf2f(unsigned short s) {
  union { unsigned u; float f; } v; v.u = ((unsigned)s) << 16;
  return v.f;
}
__device__ __forceinline__ unsigned pk2bf(float lo, float hi) {
  unsigned r;
  asm("v_cvt_pk_bf16_f32 %0, %1, %2" : "=v"(r) : "v"(lo), "v"(hi));  // RNE
  return r;
}
__device__ __forceinline__ float fexp2(float x) {
  float r; asm("v_exp_f32 %0, %1" : "=v"(r) : "v"(x)); return r;
}
__device__ __forceinline__ float frcp(float x) {
  float r; asm("v_rcp_f32 %0, %1" : "=v"(r) : "v"(x)); return r;
}
#define LOG2E 1.44269504f
__device__ __forceinline__ float fexp(float x) { return fexp2(x * LOG2E); }

// Granule layout: [128 x 32k] bf16 tile = 512 granules of 16B.
// granule g = s*64 + l: row = s*16 + (l&15), k8 = (l>>4)*8.
// h1_pk / W1T_pk / WabT_pk: panel P = rowpanel*16 + ktile (x512 granules), panels = 128 rows/cols.
// B (weights) is L2-resident -> loaded DIRECTLY global->VGPR (no LDS bounce).

// ---------------- weight pack (unchanged)
__global__ void carp_wpack(const float* __restrict__ W1, const float* __restrict__ Wa,
                           const float* __restrict__ Wb,
                           unsigned short* __restrict__ W1T_pk, unsigned short* __restrict__ WabT_pk) {
  int t = blockIdx.x * 256 + threadIdx.x;
  int mat = t >> 15;
  int gid = t & 32767;
  int g = gid & 511;
  int kt = (gid >> 9) & 15;
  int p = gid >> 13;
  int s = g >> 6, l = g & 63;
  int j = p * 128 + s * 16 + (l & 15);
  int k = kt * 32 + (l >> 4) * 8;
  unsigned short v[8];
  if (mat == 0) {
#pragma unroll
    for (int e = 0; e < 8; ++e) v[e] = f2bf(W1[(size_t)(k + e) * 512 + j]);
    *(uint4*)(W1T_pk + (size_t)gid * 8) = *(const uint4*)v;
  } else {
    int d = j >> 1;
    const float* Wx = (j & 1) ? Wb : Wa;
#pragma unroll
    for (int e = 0; e < 8; ++e) v[e] = f2bf(Wx[(size_t)(k + e) * 256 + d]);
    *(uint4*)(WabT_pk + (size_t)gid * 8) = *(const uint4*)v;
  }
}

// ---------------- GEMM1: BM=256 BN=256, 8 waves of 64x128; A reg->LDS (XOR swz), B direct L2
// LDS: A dbuf [0,64K) ([buf][rowhalf][tt][...]); epilogue image = 128KB.
__launch_bounds__(512, 2)
__global__ void carp_gemm1(const float* __restrict__ h, const unsigned short* __restrict__ W1T_pk,
                           const float* __restrict__ b1, unsigned short* __restrict__ h1_pk) {
  __shared__ __align__(16) unsigned short lds[65536];   // 128KB
  int bid0 = blockIdx.x;
  int bid = (bid0 & 7) * 128 + (bid0 >> 3);   // XCD remap, 1024 = 8*128
  int bn = bid & 1, bm = bid >> 1;
  int brow = bm * 256;
  int tid = threadIdx.x, lane = tid & 63, wid = tid >> 6;
  int wr = wid >> 1, wc = wid & 1;            // 4x2 waves: 64 rows x 128 cols each
  int pn = 2 * bn + wc;                       // this wave's B panel

  f32x4 acc[4][8] = {};
  float4 ar[8];

  int r0 = tid >> 4;            // 0..31
  int chunk = tid & 15;         // float4 k-chunk within 64-k pair
  const float* hbase = h + (size_t)(brow + r0) * 512 + chunk * 4;
  int kgA = (chunk & 7) >> 1, r16A = r0 & 15;
  int aw_const = (chunk >> 3) * 8192 + (r0 >> 4) * 1024 + kgA * 256
               + ((r16A * 16) ^ (kgA << 5) ^ ((chunk >> 3) << 4)) + (chunk & 1) * 8;
  int aread_lane = (lane >> 4) * 256 + (((lane & 15) * 16) ^ ((lane >> 4) << 5));

#define G1_LOADA(TP) do { \
  _Pragma("unroll") for (int q = 0; q < 8; ++q) \
    ar[q] = *(const float4*)(hbase + (size_t)(q * 32) * 512 + (TP) * 64); \
  } while (0)
#define G1_WRITEA(TP) do { \
  char* dstA = (char*)lds + ((TP) & 1) * 32768; \
  _Pragma("unroll") for (int q = 0; q < 8; ++q) { \
    uint2 wv; wv.x = pk2bf(ar[q].x, ar[q].y); wv.y = pk2bf(ar[q].z, ar[q].w); \
    *(uint2*)(dstA + (q >> 2) * 16384 + (q & 3) * 2048 + aw_const) = wv; \
  } } while (0)

  // prologue: A(0) to regs -> LDS buf0; A(1) in flight
  G1_LOADA(0);
  WAITVM(0);
  G1_WRITEA(0);
  G1_LOADA(1);
  WAITLGKM0;

#pragma unroll 1
  for (int tp = 0; tp < 8; ++tp) {
    // guarantee A(tp+1) reg-loads retired (16 bfr loads were issued after them)
    if (tp == 0) { WAITVM(0); } else { WAITVM(16); }
    BARRIER();                               // all waves' A(tp) LDS writes published
    if (tp < 7) G1_WRITEA(tp + 1);           // into nxt buffer (not read this iter)
    if (tp < 6) G1_LOADA(tp + 2);
    const char* Abase = (const char*)lds + (tp & 1) * 32768;
#pragma unroll
    for (int tt = 0; tt < 2; ++tt) {
      bf16x8 afr[4], bfr[8];
#pragma unroll
      for (int n = 0; n < 8; ++n)
        bfr[n] = *(const bf16x8*)(W1T_pk + ((size_t)(pn * 16 + tp * 2 + tt) * 512 + n * 64 + lane) * 8);
#pragma unroll
      for (int m = 0; m < 4; ++m) {
        int gs = wr * 4 + m;
        afr[m] = *(const bf16x8*)(Abase + (gs >> 3) * 16384 + tt * 8192
                                  + (gs & 7) * 1024 + (aread_lane ^ (tt << 4)));
      }
#pragma unroll
      for (int m = 0; m < 4; ++m)
#pragma unroll
        for (int n = 0; n < 8; ++n)
          acc[m][n] = __builtin_amdgcn_mfma_f32_16x16x32_bf16(afr[m], bfr[n], acc[m][n], 0, 0, 0);
    }
    WAITLGKM0;                               // afr reads + A writes drained before next barrier
  }
#undef G1_LOADA
#undef G1_WRITEA
  BARRIER();                                 // all waves done with LDS before image reuse

  // epilogue: +b1, relu -> 128KB granule image [rp(2)][ktc(8)][512] -> contiguous h1_pk store
  unsigned short* img = lds;
#pragma unroll
  for (int n = 0; n < 8; ++n) {
    int cl = wc * 128 + n * 16 + (lane & 15);   // local col 0..255
    float bias = b1[bn * 256 + cl];
    int ktc = cl >> 5, c32 = cl & 31;
#pragma unroll
    for (int m = 0; m < 4; ++m)
#pragma unroll
      for (int j = 0; j < 4; ++j) {
        int r = wr * 64 + m * 16 + (lane >> 4) * 4 + j;   // local row 0..255
        float v = acc[m][n][j] + bias;
        v = v > 0.f ? v : 0.f;
        int gidx = (r >> 7) * 4096 + ktc * 512 + ((r & 127) >> 4) * 64 + (c32 >> 3) * 16 + (r & 15);
        img[(size_t)gidx * 8 + (c32 & 7)] = f2bf(v);
      }
  }
  __syncthreads();
#pragma unroll
  for (int i = 0; i < 16; ++i) {
    int g = i * 512 + tid;                     // 0..8191 granules
    int P = (2 * bm + (g >> 12)) * 16 + bn * 8 + ((g >> 9) & 7);
    *(uint4*)(h1_pk + ((size_t)P * 512 + (g & 511)) * 8) = *(const uint4*)(img + (size_t)g * 8);
  }
}

// ---------------- GEMM2: BM=256 BN=256, 8 waves of 64x128; A via gload_lds, B direct L2
__launch_bounds__(512, 2)
__global__ void carp_gemm2(const unsigned short* __restrict__ h1_pk, const unsigned short* __restrict__ WabT_pk,
                           const float* __restrict__ ba, const float* __restrict__ bb,
                           const float* __restrict__ Wc, float* __restrict__ A_part) {
  __shared__ __align__(16) unsigned short lds[32768];   // 64KB: A dbuf [buf][tt][16KB]
  int bid0 = blockIdx.x;
  int bid = (bid0 & 7) * 128 + (bid0 >> 3);
  int bn = bid & 1, bm = bid >> 1;
  int tid = threadIdx.x, lane = tid & 63, wid = tid >> 6;
  int wr = wid >> 1, wc = wid & 1;
  int pn = 2 * bn + wc;

  f32x4 acc[4][8] = {};

  // A stage: 16 chunks per 32k tile; per wave 2 per tile (4 per pair)
#define G2_STAGE_A(T32, HALF, BUF) do { \
  _Pragma("unroll") for (int q = 0; q < 2; ++q) { \
    int c = wid * 2 + q; \
    int P = (2 * bm + (c >> 3)) * 16 + (T32); \
    GLOAD_LDS16(h1_pk + ((size_t)P * 512 + (c & 7) * 64 + lane) * 8, \
                (char*)lds + (BUF) * 32768 + (HALF) * 16384 + (size_t)c * 1024); \
  } } while (0)

  G2_STAGE_A(0, 0, 0); G2_STAGE_A(1, 1, 0);   // pair 0 -> buf 0 (4/wave in flight)

#pragma unroll 1
  for (int kt = 0; kt < 8; ++kt) {
    int cur = kt & 1, nxt = cur ^ 1;
    // A(kt):4 was issued before the 16 bfr loads of iter kt-1 -> vmcnt(16) retires it
    if (kt == 0) { WAITVM(0); } else { WAITVM(16); }
    BARRIER();                                // pair kt published across all waves
    if (kt < 7) { G2_STAGE_A(2 * kt + 2, 0, nxt); G2_STAGE_A(2 * kt + 3, 1, nxt); }
#pragma unroll
    for (int tt = 0; tt < 2; ++tt) {
      const char* Ab = (const char*)lds + cur * 32768 + tt * 16384;
      bf16x8 afr[4], bfr[8];
#pragma unroll
      for (int n = 0; n < 8; ++n)
        bfr[n] = *(const bf16x8*)(WabT_pk + ((size_t)(pn * 16 + 2 * kt + tt) * 512 + n * 64 + lane) * 8);
#pragma unroll
      for (int m = 0; m < 4; ++m)
        afr[m] = *(const bf16x8*)(Ab + (size_t)((wr * 4 + m) * 64 + lane) * 16);
#pragma unroll
      for (int m = 0; m < 4; ++m)
#pragma unroll
        for (int n = 0; n < 8; ++n)
          acc[m][n] = __builtin_amdgcn_mfma_f32_16x16x32_bf16(afr[m], bfr[n], acc[m][n], 0, 0, 0);
    }
    WAITLGKM0;                                // cur-buf reads drained before next barrier
  }
#undef G2_STAGE_A

  int brow = bm * 256, bcol = bn * 256;
  // epilogue: unified activation  av = c1 * rcp(1 + 2^(k*v)) + c0
  int odd = lane & 1;
  float kA = odd ? -LOG2E : -2.f * LOG2E;
  float c1 = odd ? 1.f : 2.f;
  float c0 = odd ? 0.f : -1.f;
  float rowpart[4][4] = {};
#pragma unroll
  for (int n = 0; n < 8; ++n) {
    int cg = bcol + wc * 128 + n * 16 + (lane & 15);
    int d = cg >> 1;
    float bias = (cg & 1) ? bb[d] : ba[d];
    float wcd = Wc[d];
#pragma unroll
    for (int m = 0; m < 4; ++m)
#pragma unroll
      for (int j = 0; j < 4; ++j) {
        float v = acc[m][n][j] + bias;
        float av = c1 * frcp(1.f + fexp2(kA * v)) + c0;
        float pv = av * __shfl_xor(av, 1, 64);   // a*g on both lanes of the pair
        rowpart[m][j] += pv * wcd;
      }
  }
#pragma unroll
  for (int m = 0; m < 4; ++m)
#pragma unroll
    for (int j = 0; j < 4; ++j) {
      float t = rowpart[m][j];
      t += __shfl_xor(t, 2, 64);
      t += __shfl_xor(t, 4, 64);
      t += __shfl_xor(t, 8, 64);
      rowpart[m][j] = t;
    }
  if ((lane & 15) == 0) {
    int slot = bn * 2 + wc;                    // 4 slots of 128-col partials
#pragma unroll
    for (int m = 0; m < 4; ++m)
#pragma unroll
      for (int j = 0; j < 4; ++j) {
        int row = brow + wr * 64 + m * 16 + (lane >> 4) * 4 + j;
        A_part[(size_t)row * 4 + slot] = rowpart[m][j];
      }
  }
}

// ---------------- per-bag softmax (unchanged)
__global__ void carp_softmax(const float* __restrict__ A_part, const float* __restrict__ bc,
                             float* __restrict__ A_raw_out, float* __restrict__ A_sm) {
  __shared__ float sv[8192];
  __shared__ float red[256];
  int b = blockIdx.x, tid = threadIdx.x;
  float bcv = bc[0];
  float lmax = -1e30f;
  for (int i = tid; i < 8192; i += 256) {
    float4 x = *(const float4*)(A_part + (size_t)(b * 8192 + i) * 4);
    float s = (x.x + x.y) + (x.z + x.w) + bcv;
    sv[i] = s;
    A_raw_out[b * 8192 + i] = s;
    lmax = fmaxf(lmax, s);
  }
  red[tid] = lmax;
  for (int s = 128; s > 0; s >>= 1) { __syncthreads(); if (tid < s) red[tid] = fmaxf(red[tid], red[tid + s]); }
  __syncthreads();
  float mx = red[0];
  __syncthreads();
  float lsum = 0.f;
  for (int i = tid; i < 8192; i += 256) {
    float e = fexp(sv[i] - mx);
    sv[i] = e;
    lsum += e;
  }
  red[tid] = lsum;
  for (int s = 128; s > 0; s >>= 1) { __syncthreads(); if (tid < s) red[tid] += red[tid + s]; }
  __syncthreads();
  float inv = 1.f / red[0];
  for (int i = tid; i < 8192; i += 256) A_sm[b * 8192 + i] = sv[i] * inv;
}

// ---------------- M partials (unchanged)
__global__ void carp_mkernel(const unsigned short* __restrict__ h1_pk, const float* __restrict__ A_sm,
                             float* __restrict__ Mpart) {
  __shared__ float sw[128];
  int bm = blockIdx.x;
  int tid = threadIdx.x;
  if (tid < 128) sw[tid] = A_sm[bm * 128 + tid];
  __syncthreads();
  int l = tid & 63;
  float acc[4][8] = {};
#pragma unroll
  for (int tq = 0; tq < 4; ++tq) {
    int tt = (tid >> 6) * 4 + tq;
#pragma unroll
    for (int s = 0; s < 8; ++s) {
      const unsigned short* gp = h1_pk + ((size_t)(bm * 16 + tt) * 512 + s * 64 + l) * 8;
      uint4 raw = *(const uint4*)gp;
      const unsigned short* pv = (const unsigned short*)&raw;
      float w = sw[s * 16 + (l & 15)];
#pragma unroll
      for (int e = 0; e < 8; ++e) acc[tq][e] += w * bf2f(pv[e]);
    }
  }
#pragma unroll
  for (int tq = 0; tq < 4; ++tq)
#pragma unroll
    for (int e = 0; e < 8; ++e) {
      float t = acc[tq][e];
      t += __shfl_xor(t, 1, 64);
      t += __shfl_xor(t, 2, 64);
      t += __shfl_xor(t, 4, 64);
      t += __shfl_xor(t, 8, 64);
      acc[tq][e] = t;
    }
  if ((l & 15) == 0) {
    int cc = (l >> 4) & 3;
#pragma unroll
    for (int tq = 0; tq < 4; ++tq) {
      int tt = (tid >> 6) * 4 + tq;
      float* mp = Mpart + (size_t)bm * 512 + tt * 32 + cc * 8;
#pragma unroll
      for (int e = 0; e < 8; ++e) mp[e] = acc[tq][e];
    }
  }
}

// ---------------- final (unchanged)
__global__ void carp_final(const float* __restrict__ Mpart, const float* __restrict__ Wcls,
                           const float* __restrict__ bcls, float* __restrict__ out) {
  __shared__ float ctx[512];
  int t = threadIdx.x;
  float c = 0.f;
  for (int b = 0; b < 16; ++b) {
    float s = 0.f;
    for (int p = 0; p < 64; ++p) s += Mpart[((size_t)(b * 64 + p) << 9) + t];
    out[131077 + b * 512 + t] = s;
    c += s;
  }
  ctx[t] = c * (1.f / 16.f);
  __syncthreads();
  if (t < 64) {
    float p0 = 0.f, p1 = 0.f;
    for (int hh = t; hh < 512; hh += 64) {
      float cv = ctx[hh];
      p0 += cv * Wcls[hh * 2];
      p1 += cv * Wcls[hh * 2 + 1];
    }
    for (int m = 1; m < 64; m <<= 1) { p0 += __shfl_xor(p0, m, 64); p1 += __shfl_xor(p1, m, 64); }
    if (t == 0) {
      float l0 = p0 + bcls[0], l1 = p1 + bcls[1];
      out[0] = l0; out[1] = l1;
      float mx = fmaxf(l0, l1);
      float e0 = expf(l0 - mx), e1 = expf(l1 - mx);
      float s = e0 + e1;
      out[2] = e0 / s; out[3] = e1 / s;
      out[4] = (l1 > l0) ? 1.0f : 0.0f;
    }
  }
}

extern "C" void kernel_launch(void* const* d_in, const int* in_sizes, int n_in,
                              void* d_out, int out_size, void* d_ws, size_t ws_size,
                              hipStream_t stream) {
  const float* h    = (const float*)d_in[0];
  const float* W1   = (const float*)d_in[1];
  const float* b1   = (const float*)d_in[2];
  const float* Wa   = (const float*)d_in[3];
  const float* ba   = (const float*)d_in[4];
  const float* Wb   = (const float*)d_in[5];
  const float* bb   = (const float*)d_in[6];
  const float* Wc   = (const float*)d_in[7];
  const float* bc   = (const float*)d_in[8];
  const float* Wcls = (const float*)d_in[9];
  const float* bcls = (const float*)d_in[10];
  float* out = (float*)d_out;

  char* ws = (char*)d_ws;
  unsigned short* h1_pk   = (unsigned short*)(ws);                  // 134,217,728 B
  unsigned short* W1T_pk  = (unsigned short*)(ws + 134217728);      //     524,288 B
  unsigned short* WabT_pk = (unsigned short*)(ws + 134742016);      //     524,288 B
  float* A_part           = (float*)(ws + 135266304);               //   2,097,152 B used
  float* A_sm             = (float*)(ws + 139460608);               //     524,288 B
  float* Mpart            = (float*)(ws + 135266304);               //   overlays A_part

  carp_wpack  <<<256,  256, 0, stream>>>(W1, Wa, Wb, W1T_pk, WabT_pk);
  carp_gemm1  <<<1024, 512, 0, stream>>>(h, W1T_pk, b1, h1_pk);
  carp_gemm2  <<<1024, 512, 0, stream>>>(h1_pk, WabT_pk, ba, bb, Wc, A_part);
  carp_softmax<<<16,   256, 0, stream>>>(A_part, bc, out + 5, A_sm);
  carp_mkernel<<<1024, 256, 0, stream>>>(h1_pk, A_sm, Mpart);
  carp_final  <<<1,    512, 0, stream>>>(Mpart, Wcls, bcls, out);
}

// Round 17
// 304.866 us; speedup vs baseline: 1.1478x; 1.1478x over previous
//
#include <hip/hip_runtime.h>
#include <math.h>

typedef short bf16x8 __attribute__((ext_vector_type(8)));
typedef float f32x4  __attribute__((ext_vector_type(4)));

#define GLOAD_LDS16(SRC, DST) \
  __builtin_amdgcn_global_load_lds((const __attribute__((address_space(1))) void*)(SRC), \
      (__attribute__((address_space(3))) void*)(DST), 16, 0, 0)

#define WAITVM(N) asm volatile("s_waitcnt vmcnt(" #N ")" ::: "memory")
#define WAITLGKM0 asm volatile("s_waitcnt lgkmcnt(0)" ::: "memory")
#define BARRIER() do { __builtin_amdgcn_s_barrier(); asm volatile("" ::: "memory"); } while (0)

__device__ __forceinline__ unsigned short f2bf(float f) {
  union { float f; unsigned u; } v; v.f = f;
  unsigned r = v.u + 0x7FFFu + ((v.u >> 16) & 1u);   // RNE
  return (unsigned short)(r >> 16);
}
__device__ __forceinline__ float bf2f(unsigned short s) {
  union { unsigned u; float f; } v; v.u = ((unsigned)s) << 16;
  return v.f;
}
__device__ __forceinline__ unsigned pk2bf(float lo, float hi) {
  unsigned r;
  asm("v_cvt_pk_bf16_f32 %0, %1, %2" : "=v"(r) : "v"(lo), "v"(hi));  // RNE
  return r;
}
__device__ __forceinline__ float fexp2(float x) {
  float r; asm("v_exp_f32 %0, %1" : "=v"(r) : "v"(x)); return r;
}
__device__ __forceinline__ float frcp(float x) {
  float r; asm("v_rcp_f32 %0, %1" : "=v"(r) : "v"(x)); return r;
}
#define LOG2E 1.44269504f
__device__ __forceinline__ float fexp(float x) { return fexp2(x * LOG2E); }

// Granule layout: [128 x 32k] bf16 tile = 512 granules of 16B.
// granule g = s*64 + l: row = s*16 + (l&15), k8 = (l>>4)*8.
// h1_pk / W1T_pk / WabT_pk: panel P = rowpanel*16 + ktile (x512 granules), panels = 128 cols.
// WabT panel layout (NEW): within panel pn, local col c<64 = Wa[:, pn*64+c]; c>=64 = Wb[:, pn*64+c-64].
// -> in gemm2, lane's acc[m][n] (n<4) is the a-preact and acc[m][n+4] the g-preact of the SAME d.

// ---------------- weight pack
__global__ void carp_wpack(const float* __restrict__ W1, const float* __restrict__ Wa,
                           const float* __restrict__ Wb,
                           unsigned short* __restrict__ W1T_pk, unsigned short* __restrict__ WabT_pk) {
  int t = blockIdx.x * 256 + threadIdx.x;
  int mat = t >> 15;
  int gid = t & 32767;
  int g = gid & 511;
  int kt = (gid >> 9) & 15;
  int p = gid >> 13;
  int s = g >> 6, l = g & 63;
  int k = kt * 32 + (l >> 4) * 8;
  unsigned short v[8];
  if (mat == 0) {
    int j = p * 128 + s * 16 + (l & 15);
#pragma unroll
    for (int e = 0; e < 8; ++e) v[e] = f2bf(W1[(size_t)(k + e) * 512 + j]);
    *(uint4*)(W1T_pk + (size_t)gid * 8) = *(const uint4*)v;
  } else {
    int lc = s * 16 + (l & 15);              // local col in panel, 0..127
    int d = p * 64 + (lc & 63);
    const float* Wx = (lc >> 6) ? Wb : Wa;
#pragma unroll
    for (int e = 0; e < 8; ++e) v[e] = f2bf(Wx[(size_t)(k + e) * 256 + d]);
    *(uint4*)(WabT_pk + (size_t)gid * 8) = *(const uint4*)v;
  }
}

// ---------------- GEMM1: BM=256 BN=256 BK=64-pair, 8 waves of 64x128 (R15 structure)
// LDS 128KB: A dbuf [0,64K); B dbuf [64K,128K); epilogue image = all 128KB.
__launch_bounds__(512, 2)
__global__ void carp_gemm1(const float* __restrict__ h, const unsigned short* __restrict__ W1T_pk,
                           const float* __restrict__ b1, unsigned short* __restrict__ h1_pk) {
  __shared__ __align__(16) unsigned short lds[65536];   // 128KB
  int bid0 = blockIdx.x;
  int bid = (bid0 & 7) * 128 + (bid0 >> 3);   // XCD remap, 1024 = 8*128
  int bn = bid & 1, bm = bid >> 1;
  int brow = bm * 256;
  int tid = threadIdx.x, lane = tid & 63, wid = tid >> 6;
  int wr = wid >> 1, wc = wid & 1;            // 4x2 waves: 64 rows x 128 cols each

  f32x4 acc[4][8] = {};
  float4 ar[8];

  int r0 = tid >> 4;            // 0..31
  int chunk = tid & 15;         // float4 k-chunk within 64-k pair
  const float* hbase = h + (size_t)(brow + r0) * 512 + chunk * 4;
  int kgA = (chunk & 7) >> 1, r16A = r0 & 15;
  int aw_const = (chunk >> 3) * 8192 + (r0 >> 4) * 1024 + kgA * 256
               + ((r16A * 16) ^ (kgA << 5) ^ ((chunk >> 3) << 4)) + (chunk & 1) * 8;
  int aread_lane = (lane >> 4) * 256 + (((lane & 15) * 16) ^ ((lane >> 4) << 5));

#define G1_LOADA(TP) do { \
  _Pragma("unroll") for (int q = 0; q < 8; ++q) \
    ar[q] = *(const float4*)(hbase + (size_t)(q * 32) * 512 + (TP) * 64); \
  } while (0)
#define G1_WRITEA(TP) do { \
  char* dstA = (char*)lds + ((TP) & 1) * 32768; \
  _Pragma("unroll") for (int q = 0; q < 8; ++q) { \
    uint2 wv; wv.x = pk2bf(ar[q].x, ar[q].y); wv.y = pk2bf(ar[q].z, ar[q].w); \
    *(uint2*)(dstA + (q >> 2) * 16384 + (q & 3) * 2048 + aw_const) = wv; \
  } } while (0)
#define G1_STAGEB(TP, BUF) do { \
  _Pragma("unroll") for (int q = 0; q < 4; ++q) { \
    int c = wid * 4 + q; \
    int pn = 2 * bn + ((c & 15) >> 3); \
    GLOAD_LDS16(W1T_pk + ((size_t)(pn * 16 + (TP) * 2 + (c >> 4)) * 512 + (c & 7) * 64 + lane) * 8, \
                (char*)lds + 65536 + (BUF) * 32768 + (size_t)c * 1024); \
  } } while (0)

  // prologue
  G1_LOADA(0);
  WAITVM(0);
  G1_WRITEA(0);
  G1_STAGEB(0, 0);                  // B0:4
  G1_LOADA(1);                      // + A1:8 -> 12
  WAITLGKM0;

#pragma unroll 1
  for (int tp = 0; tp < 8; ++tp) {
    if (tp < 7) G1_STAGEB(tp + 1, (tp + 1) & 1);      // B(tp)4, A(tp+1)8, B(tp+1)4 = 16
    if (tp < 7) { WAITVM(12); } else { WAITVM(0); }   // B(tp) landed
    BARRIER();                                         // pair tp published
    const char* Abase = (const char*)lds + (tp & 1) * 32768;
    const char* Bbase = (const char*)lds + 65536 + (tp & 1) * 32768;
#pragma unroll
    for (int tt = 0; tt < 2; ++tt) {
      bf16x8 afr[4], bfr[8];
#pragma unroll
      for (int m = 0; m < 4; ++m) {
        int gs = wr * 4 + m;
        afr[m] = *(const bf16x8*)(Abase + (gs >> 3) * 16384 + tt * 8192
                                  + (gs & 7) * 1024 + (aread_lane ^ (tt << 4)));
      }
#pragma unroll
      for (int n = 0; n < 8; ++n)
        bfr[n] = *(const bf16x8*)(Bbase + tt * 16384 + wc * 8192
                                  + (size_t)(n * 64 + lane) * 16);
#pragma unroll
      for (int m = 0; m < 4; ++m)
#pragma unroll
        for (int n = 0; n < 8; ++n)
          acc[m][n] = __builtin_amdgcn_mfma_f32_16x16x32_bf16(afr[m], bfr[n], acc[m][n], 0, 0, 0);
    }
    if (tp < 7) { WAITVM(4); G1_WRITEA(tp + 1); }     // A(tp+1) landed; B(tp+1) in flight
    if (tp < 6) G1_LOADA(tp + 2);
    WAITLGKM0;
    BARRIER();
  }
#undef G1_LOADA
#undef G1_WRITEA
#undef G1_STAGEB

  // epilogue: +b1, relu -> 128KB granule image [rp(2)][ktc(8)][512] -> contiguous h1_pk store
  unsigned short* img = lds;
#pragma unroll
  for (int n = 0; n < 8; ++n) {
    int cl = wc * 128 + n * 16 + (lane & 15);   // local col 0..255
    float bias = b1[bn * 256 + cl];
    int ktc = cl >> 5, c32 = cl & 31;
#pragma unroll
    for (int m = 0; m < 4; ++m)
#pragma unroll
      for (int j = 0; j < 4; ++j) {
        int r = wr * 64 + m * 16 + (lane >> 4) * 4 + j;   // local row 0..255
        float v = acc[m][n][j] + bias;
        v = v > 0.f ? v : 0.f;
        int gidx = (r >> 7) * 4096 + ktc * 512 + ((r & 127) >> 4) * 64 + (c32 >> 3) * 16 + (r & 15);
        img[(size_t)gidx * 8 + (c32 & 7)] = f2bf(v);
      }
  }
  __syncthreads();
#pragma unroll
  for (int i = 0; i < 16; ++i) {
    int g = i * 512 + tid;                     // 0..8191 granules
    int P = (2 * bm + (g >> 12)) * 16 + bn * 8 + ((g >> 9) & 7);
    *(uint4*)(h1_pk + ((size_t)P * 512 + (g & 511)) * 8) = *(const uint4*)(img + (size_t)g * 8);
  }
}

// ---------------- GEMM2: BM=256 BN=256, 8 waves of 64x128 (R15 structure), lane-local a/g pairing
#define G2_STAGE(T32, HALF, BUF) do { \
  _Pragma("unroll") for (int q = 0; q < 2; ++q) { \
    int c = wid * 2 + q; \
    int P = (2 * bm + (c >> 3)) * 16 + (T32); \
    GLOAD_LDS16(h1_pk + ((size_t)P * 512 + (c & 7) * 64 + lane) * 8, \
                (char*)lds + (BUF) * 32768 + (HALF) * 16384 + (size_t)c * 1024); \
  } \
  _Pragma("unroll") for (int q = 0; q < 2; ++q) { \
    int c2 = wid * 2 + q; \
    int pn = 2 * bn + (c2 >> 3); \
    GLOAD_LDS16(WabT_pk + ((size_t)(pn * 16 + (T32)) * 512 + (c2 & 7) * 64 + lane) * 8, \
                (char*)lds + 65536 + (BUF) * 32768 + (HALF) * 16384 + (size_t)c2 * 1024); \
  } } while (0)

__launch_bounds__(512, 2)
__global__ void carp_gemm2(const unsigned short* __restrict__ h1_pk, const unsigned short* __restrict__ WabT_pk,
                           const float* __restrict__ ba, const float* __restrict__ bb,
                           const float* __restrict__ Wc, float* __restrict__ A_part) {
  __shared__ __align__(16) unsigned short lds[65536];   // 128KB: A [0,64K), B [64K,128K)
  int bid0 = blockIdx.x;
  int bid = (bid0 & 7) * 128 + (bid0 >> 3);
  int bn = bid & 1, bm = bid >> 1;
  int tid = threadIdx.x, lane = tid & 63, wid = tid >> 6;
  int wr = wid >> 1, wc = wid & 1;

  f32x4 acc[4][8] = {};

  G2_STAGE(0, 0, 0); G2_STAGE(1, 1, 0);   // 8/wave outstanding

#pragma unroll 1
  for (int kt = 0; kt < 8; ++kt) {
    int cur = kt & 1, nxt = cur ^ 1;
    if (kt < 7) { G2_STAGE(2 * kt + 2, 0, nxt); G2_STAGE(2 * kt + 3, 1, nxt); }
    if (kt < 7) { WAITVM(8); } else { WAITVM(0); }   // pair kt landed
    BARRIER();
#pragma unroll
    for (int tt = 0; tt < 2; ++tt) {
      const char* Ab = (const char*)lds + cur * 32768 + tt * 16384;
      const char* Bb = (const char*)lds + 65536 + cur * 32768 + tt * 16384 + wc * 8192;
      bf16x8 afr[4], bfr[8];
#pragma unroll
      for (int m = 0; m < 4; ++m)
        afr[m] = *(const bf16x8*)(Ab + (size_t)((wr * 4 + m) * 64 + lane) * 16);
#pragma unroll
      for (int n = 0; n < 8; ++n)
        bfr[n] = *(const bf16x8*)(Bb + (size_t)(n * 64 + lane) * 16);
#pragma unroll
      for (int m = 0; m < 4; ++m)
#pragma unroll
        for (int n = 0; n < 8; ++n)
          acc[m][n] = __builtin_amdgcn_mfma_f32_16x16x32_bf16(afr[m], bfr[n], acc[m][n], 0, 0, 0);
    }
    WAITLGKM0;
    BARRIER();
  }

  int brow = bm * 256;
  int pn = 2 * bn + wc;
  // epilogue: lane-local a/g pairing. acc[m][n] (n<4) = a-preact of d = pn*64 + n*16 + (lane&15);
  // acc[m][n+4] = g-preact of the SAME d. No cross-lane pairing needed.
  float rowpart[4][4] = {};
#pragma unroll
  for (int n = 0; n < 4; ++n) {
    int d = pn * 64 + n * 16 + (lane & 15);
    float ba_ = ba[d], bb_ = bb[d], wcd = Wc[d];
#pragma unroll
    for (int m = 0; m < 4; ++m)
#pragma unroll
      for (int j = 0; j < 4; ++j) {
        float va = acc[m][n][j] + ba_;
        float vg = acc[m][n + 4][j] + bb_;
        float a = 2.f * frcp(1.f + fexp2(-2.f * LOG2E * va)) - 1.f;   // tanh
        float g = frcp(1.f + fexp2(-LOG2E * vg));                      // sigmoid
        rowpart[m][j] += a * g * wcd;
      }
  }
  // reduce over the 16 lanes of the group (16 distinct d per n already summed in rowpart loop)
#pragma unroll
  for (int m = 0; m < 4; ++m)
#pragma unroll
    for (int j = 0; j < 4; ++j) {
      float t = rowpart[m][j];
      t += __shfl_xor(t, 1, 64);
      t += __shfl_xor(t, 2, 64);
      t += __shfl_xor(t, 4, 64);
      t += __shfl_xor(t, 8, 64);
      rowpart[m][j] = t;
    }
  if ((lane & 15) == 0) {
    int slot = bn * 2 + wc;                    // 4 slots of 128-col partials
#pragma unroll
    for (int m = 0; m < 4; ++m)
#pragma unroll
      for (int j = 0; j < 4; ++j) {
        int row = brow + wr * 64 + m * 16 + (lane >> 4) * 4 + j;
        A_part[(size_t)row * 4 + slot] = rowpart[m][j];
      }
  }
}
#undef G2_STAGE

// ---------------- per-bag softmax (unchanged)
__global__ void carp_softmax(const float* __restrict__ A_part, const float* __restrict__ bc,
                             float* __restrict__ A_raw_out, float* __restrict__ A_sm) {
  __shared__ float sv[8192];
  __shared__ float red[256];
  int b = blockIdx.x, tid = threadIdx.x;
  float bcv = bc[0];
  float lmax = -1e30f;
  for (int i = tid; i < 8192; i += 256) {
    float4 x = *(const float4*)(A_part + (size_t)(b * 8192 + i) * 4);
    float s = (x.x + x.y) + (x.z + x.w) + bcv;
    sv[i] = s;
    A_raw_out[b * 8192 + i] = s;
    lmax = fmaxf(lmax, s);
  }
  red[tid] = lmax;
  for (int s = 128; s > 0; s >>= 1) { __syncthreads(); if (tid < s) red[tid] = fmaxf(red[tid], red[tid + s]); }
  __syncthreads();
  float mx = red[0];
  __syncthreads();
  float lsum = 0.f;
  for (int i = tid; i < 8192; i += 256) {
    float e = fexp(sv[i] - mx);
    sv[i] = e;
    lsum += e;
  }
  red[tid] = lsum;
  for (int s = 128; s > 0; s >>= 1) { __syncthreads(); if (tid < s) red[tid] += red[tid + s]; }
  __syncthreads();
  float inv = 1.f / red[0];
  for (int i = tid; i < 8192; i += 256) A_sm[b * 8192 + i] = sv[i] * inv;
}

// ---------------- M partials (unchanged)
__global__ void carp_mkernel(const unsigned short* __restrict__ h1_pk, const float* __restrict__ A_sm,
                             float* __restrict__ Mpart) {
  __shared__ float sw[128];
  int bm = blockIdx.x;
  int tid = threadIdx.x;
  if (tid < 128) sw[tid] = A_sm[bm * 128 + tid];
  __syncthreads();
  int l = tid & 63;
  float acc[4][8] = {};
#pragma unroll
  for (int tq = 0; tq < 4; ++tq) {
    int tt = (tid >> 6) * 4 + tq;
#pragma unroll
    for (int s = 0; s < 8; ++s) {
      const unsigned short* gp = h1_pk + ((size_t)(bm * 16 + tt) * 512 + s * 64 + l) * 8;
      uint4 raw = *(const uint4*)gp;
      const unsigned short* pv = (const unsigned short*)&raw;
      float w = sw[s * 16 + (l & 15)];
#pragma unroll
      for (int e = 0; e < 8; ++e) acc[tq][e] += w * bf2f(pv[e]);
    }
  }
#pragma unroll
  for (int tq = 0; tq < 4; ++tq)
#pragma unroll
    for (int e = 0; e < 8; ++e) {
      float t = acc[tq][e];
      t += __shfl_xor(t, 1, 64);
      t += __shfl_xor(t, 2, 64);
      t += __shfl_xor(t, 4, 64);
      t += __shfl_xor(t, 8, 64);
      acc[tq][e] = t;
    }
  if ((l & 15) == 0) {
    int cc = (l >> 4) & 3;
#pragma unroll
    for (int tq = 0; tq < 4; ++tq) {
      int tt = (tid >> 6) * 4 + tq;
      float* mp = Mpart + (size_t)bm * 512 + tt * 32 + cc * 8;
#pragma unroll
      for (int e = 0; e < 8; ++e) mp[e] = acc[tq][e];
    }
  }
}

// ---------------- final (unchanged)
__global__ void carp_final(const float* __restrict__ Mpart, const float* __restrict__ Wcls,
                           const float* __restrict__ bcls, float* __restrict__ out) {
  __shared__ float ctx[512];
  int t = threadIdx.x;
  float c = 0.f;
  for (int b = 0; b < 16; ++b) {
    float s = 0.f;
    for (int p = 0; p < 64; ++p) s += Mpart[((size_t)(b * 64 + p) << 9) + t];
    out[131077 + b * 512 + t] = s;
    c += s;
  }
  ctx[t] = c * (1.f / 16.f);
  __syncthreads();
  if (t < 64) {
    float p0 = 0.f, p1 = 0.f;
    for (int hh = t; hh < 512; hh += 64) {
      float cv = ctx[hh];
      p0 += cv * Wcls[hh * 2];
      p1 += cv * Wcls[hh * 2 + 1];
    }
    for (int m = 1; m < 64; m <<= 1) { p0 += __shfl_xor(p0, m, 64); p1 += __shfl_xor(p1, m, 64); }
    if (t == 0) {
      float l0 = p0 + bcls[0], l1 = p1 + bcls[1];
      out[0] = l0; out[1] = l1;
      float mx = fmaxf(l0, l1);
      float e0 = expf(l0 - mx), e1 = expf(l1 - mx);
      float s = e0 + e1;
      out[2] = e0 / s; out[3] = e1 / s;
      out[4] = (l1 > l0) ? 1.0f : 0.0f;
    }
  }
}

extern "C" void kernel_launch(void* const* d_in, const int* in_sizes, int n_in,
                              void* d_out, int out_size, void* d_ws, size_t ws_size,
                              hipStream_t stream) {
  const float* h    = (const float*)d_in[0];
  const float* W1   = (const float*)d_in[1];
  const float* b1   = (const float*)d_in[2];
  const float* Wa   = (const float*)d_in[3];
  const float* ba   = (const float*)d_in[4];
  const float* Wb   = (const float*)d_in[5];
  const float* bb   = (const float*)d_in[6];
  const float* Wc   = (const float*)d_in[7];
  const float* bc   = (const float*)d_in[8];
  const float* Wcls = (const float*)d_in[9];
  const float* bcls = (const float*)d_in[10];
  float* out = (float*)d_out;

  char* ws = (char*)d_ws;
  unsigned short* h1_pk   = (unsigned short*)(ws);                  // 134,217,728 B
  unsigned short* W1T_pk  = (unsigned short*)(ws + 134217728);      //     524,288 B
  unsigned short* WabT_pk = (unsigned short*)(ws + 134742016);      //     524,288 B
  float* A_part           = (float*)(ws + 135266304);               //   2,097,152 B used
  float* A_sm             = (float*)(ws + 139460608);               //     524,288 B
  float* Mpart            = (float*)(ws + 135266304);               //   overlays A_part

  carp_wpack  <<<256,  256, 0, stream>>>(W1, Wa, Wb, W1T_pk, WabT_pk);
  carp_gemm1  <<<1024, 512, 0, stream>>>(h, W1T_pk, b1, h1_pk);
  carp_gemm2  <<<1024, 512, 0, stream>>>(h1_pk, WabT_pk, ba, bb, Wc, A_part);
  carp_softmax<<<16,   256, 0, stream>>>(A_part, bc, out + 5, A_sm);
  carp_mkernel<<<1024, 256, 0, stream>>>(h1_pk, A_sm, Mpart);
  carp_final  <<<1,    512, 0, stream>>>(Mpart, Wcls, bcls, out);
}

// Round 19
// 297.426 us; speedup vs baseline: 1.1765x; 1.0250x over previous
//
#include <hip/hip_runtime.h>
#include <math.h>

typedef short bf16x8 __attribute__((ext_vector_type(8)));
typedef float f32x4  __attribute__((ext_vector_type(4)));

#define GLOAD_LDS16(SRC, DST) \
  __builtin_amdgcn_global_load_lds((const __attribute__((address_space(1))) void*)(SRC), \
      (__attribute__((address_space(3))) void*)(DST), 16, 0, 0)

#define WAITVM(N) asm volatile("s_waitcnt vmcnt(" #N ")" ::: "memory")
#define WAITLGKM0 asm volatile("s_waitcnt lgkmcnt(0)" ::: "memory")
#define BARRIER() do { __builtin_amdgcn_s_barrier(); asm volatile("" ::: "memory"); } while (0)

__device__ __forceinline__ unsigned short f2bf(float f) {
  union { float f; unsigned u; } v; v.f = f;
  unsigned r = v.u + 0x7FFFu + ((v.u >> 16) & 1u);   // RNE
  return (unsigned short)(r >> 16);
}
__device__ __forceinline__ float bf2f(unsigned short s) {
  union { unsigned u; float f; } v; v.u = ((unsigned)s) << 16;
  return v.f;
}
__device__ __forceinline__ unsigned pk2bf(float lo, float hi) {
  unsigned r;
  asm("v_cvt_pk_bf16_f32 %0, %1, %2" : "=v"(r) : "v"(lo), "v"(hi));  // RNE
  return r;
}
__device__ __forceinline__ float fexp2(float x) {
  float r; asm("v_exp_f32 %0, %1" : "=v"(r) : "v"(x)); return r;
}
__device__ __forceinline__ float frcp(float x) {
  float r; asm("v_rcp_f32 %0, %1" : "=v"(r) : "v"(x)); return r;
}
#define LOG2E 1.44269504f
__device__ __forceinline__ float fexp(float x) { return fexp2(x * LOG2E); }

// Granule layout: [128 x 32k] bf16 tile = 512 granules of 16B.
// granule g = s*64 + l: row = s*16 + (l&15), k8 = (l>>4)*8.
// h1_pk / W1T_pk / WabT_pk: panel P = rowpanel*16 + ktile (x512 granules), panels = 128 cols.
// WabT panel pn: local col c<64 = Wa[:, pn*64+c]; c>=64 = Wb[:, pn*64+c-64]
// -> gemm2 lane-local a/g pairing: acc[m][n] vs acc[m][n+4] same d.

// ---------------- weight pack (unchanged)
__global__ void carp_wpack(const float* __restrict__ W1, const float* __restrict__ Wa,
                           const float* __restrict__ Wb,
                           unsigned short* __restrict__ W1T_pk, unsigned short* __restrict__ WabT_pk) {
  int t = blockIdx.x * 256 + threadIdx.x;
  int mat = t >> 15;
  int gid = t & 32767;
  int g = gid & 511;
  int kt = (gid >> 9) & 15;
  int p = gid >> 13;
  int s = g >> 6, l = g & 63;
  int k = kt * 32 + (l >> 4) * 8;
  unsigned short v[8];
  if (mat == 0) {
    int j = p * 128 + s * 16 + (l & 15);
#pragma unroll
    for (int e = 0; e < 8; ++e) v[e] = f2bf(W1[(size_t)(k + e) * 512 + j]);
    *(uint4*)(W1T_pk + (size_t)gid * 8) = *(const uint4*)v;
  } else {
    int lc = s * 16 + (l & 15);
    int d = p * 64 + (lc & 63);
    const float* Wx = (lc >> 6) ? Wb : Wa;
#pragma unroll
    for (int e = 0; e < 8; ++e) v[e] = f2bf(Wx[(size_t)(k + e) * 256 + d]);
    *(uint4*)(WabT_pk + (size_t)gid * 8) = *(const uint4*)v;
  }
}

// ---------------- GEMM1: R17 loop ordering restored (WRITEA before LOADA — single ar[8] is safe)
__launch_bounds__(512, 2)
__global__ void carp_gemm1(const float* __restrict__ h, const unsigned short* __restrict__ W1T_pk,
                           const float* __restrict__ b1, unsigned short* __restrict__ h1_pk) {
  __shared__ __align__(16) unsigned short lds[65536];   // 128KB
  int bid0 = blockIdx.x;
  int bid = (bid0 & 7) * 128 + (bid0 >> 3);   // XCD remap, 1024 = 8*128
  int bn = bid & 1, bm = bid >> 1;
  int brow = bm * 256;
  int tid = threadIdx.x, lane = tid & 63, wid = tid >> 6;
  int wr = wid >> 1, wc = wid & 1;            // 4x2 waves: 64 rows x 128 cols each

  f32x4 acc[4][8] = {};
  float4 ar[8];

  int r0 = tid >> 4;
  int chunk = tid & 15;
  const float* hbase = h + (size_t)(brow + r0) * 512 + chunk * 4;
  int kgA = (chunk & 7) >> 1, r16A = r0 & 15;
  int aw_const = (chunk >> 3) * 8192 + (r0 >> 4) * 1024 + kgA * 256
               + ((r16A * 16) ^ (kgA << 5) ^ ((chunk >> 3) << 4)) + (chunk & 1) * 8;
  int aread_lane = (lane >> 4) * 256 + (((lane & 15) * 16) ^ ((lane >> 4) << 5));

#define G1_LOADA(TP) do { \
  _Pragma("unroll") for (int q = 0; q < 8; ++q) \
    ar[q] = *(const float4*)(hbase + (size_t)(q * 32) * 512 + (TP) * 64); \
  } while (0)
#define G1_WRITEA(TP) do { \
  char* dstA = (char*)lds + ((TP) & 1) * 32768; \
  _Pragma("unroll") for (int q = 0; q < 8; ++q) { \
    uint2 wv; wv.x = pk2bf(ar[q].x, ar[q].y); wv.y = pk2bf(ar[q].z, ar[q].w); \
    *(uint2*)(dstA + (q >> 2) * 16384 + (q & 3) * 2048 + aw_const) = wv; \
  } } while (0)
#define G1_STAGEB(TP, BUF) do { \
  _Pragma("unroll") for (int q = 0; q < 4; ++q) { \
    int c = wid * 4 + q; \
    int pn = 2 * bn + ((c & 15) >> 3); \
    GLOAD_LDS16(W1T_pk + ((size_t)(pn * 16 + (TP) * 2 + (c >> 4)) * 512 + (c & 7) * 64 + lane) * 8, \
                (char*)lds + 65536 + (BUF) * 32768 + (size_t)c * 1024); \
  } } while (0)

  // prologue
  G1_LOADA(0);
  WAITVM(0);
  G1_WRITEA(0);
  G1_STAGEB(0, 0);                  // B0:4
  G1_LOADA(1);                      // + A1:8 -> 12
  WAITLGKM0;

#pragma unroll 1
  for (int tp = 0; tp < 8; ++tp) {
    if (tp < 7) G1_STAGEB(tp + 1, (tp + 1) & 1);      // B(tp)4, A(tp+1)8, B(tp+1)4 = 16
    if (tp < 7) { WAITVM(12); } else { WAITVM(0); }   // B(tp) landed
    BARRIER();                                         // pair tp published
    const char* Abase = (const char*)lds + (tp & 1) * 32768;
    const char* Bbase = (const char*)lds + 65536 + (tp & 1) * 32768;
#pragma unroll
    for (int tt = 0; tt < 2; ++tt) {
      bf16x8 afr[4], bfr[8];
#pragma unroll
      for (int m = 0; m < 4; ++m) {
        int gs = wr * 4 + m;
        afr[m] = *(const bf16x8*)(Abase + (gs >> 3) * 16384 + tt * 8192
                                  + (gs & 7) * 1024 + (aread_lane ^ (tt << 4)));
      }
#pragma unroll
      for (int n = 0; n < 8; ++n)
        bfr[n] = *(const bf16x8*)(Bbase + tt * 16384 + wc * 8192
                                  + (size_t)(n * 64 + lane) * 16);
#pragma unroll
      for (int m = 0; m < 4; ++m)
#pragma unroll
        for (int n = 0; n < 8; ++n)
          acc[m][n] = __builtin_amdgcn_mfma_f32_16x16x32_bf16(afr[m], bfr[n], acc[m][n], 0, 0, 0);
    }
    if (tp < 7) { WAITVM(4); G1_WRITEA(tp + 1); }     // A(tp+1) landed; THEN reload ar
    if (tp < 6) G1_LOADA(tp + 2);
    WAITLGKM0;
    BARRIER();
  }
#undef G1_LOADA
#undef G1_WRITEA
#undef G1_STAGEB

  // epilogue: +b1, relu -> 128KB granule image -> contiguous h1_pk store
  unsigned short* img = lds;
#pragma unroll
  for (int n = 0; n < 8; ++n) {
    int cl = wc * 128 + n * 16 + (lane & 15);
    float bias = b1[bn * 256 + cl];
    int ktc = cl >> 5, c32 = cl & 31;
#pragma unroll
    for (int m = 0; m < 4; ++m)
#pragma unroll
      for (int j = 0; j < 4; ++j) {
        int r = wr * 64 + m * 16 + (lane >> 4) * 4 + j;
        float v = acc[m][n][j] + bias;
        v = v > 0.f ? v : 0.f;
        int gidx = (r >> 7) * 4096 + ktc * 512 + ((r & 127) >> 4) * 64 + (c32 >> 3) * 16 + (r & 15);
        img[(size_t)gidx * 8 + (c32 & 7)] = f2bf(v);
      }
  }
  __syncthreads();
#pragma unroll
  for (int i = 0; i < 16; ++i) {
    int g = i * 512 + tid;
    int P = (2 * bm + (g >> 12)) * 16 + bn * 8 + ((g >> 9) & 7);
    *(uint4*)(h1_pk + ((size_t)P * 512 + (g & 511)) * 8) = *(const uint4*)(img + (size_t)g * 8);
  }
}

// ---------------- GEMM2 (unchanged from R17)
#define G2_STAGE(T32, HALF, BUF) do { \
  _Pragma("unroll") for (int q = 0; q < 2; ++q) { \
    int c = wid * 2 + q; \
    int P = (2 * bm + (c >> 3)) * 16 + (T32); \
    GLOAD_LDS16(h1_pk + ((size_t)P * 512 + (c & 7) * 64 + lane) * 8, \
                (char*)lds + (BUF) * 32768 + (HALF) * 16384 + (size_t)c * 1024); \
  } \
  _Pragma("unroll") for (int q = 0; q < 2; ++q) { \
    int c2 = wid * 2 + q; \
    int pn = 2 * bn + (c2 >> 3); \
    GLOAD_LDS16(WabT_pk + ((size_t)(pn * 16 + (T32)) * 512 + (c2 & 7) * 64 + lane) * 8, \
                (char*)lds + 65536 + (BUF) * 32768 + (HALF) * 16384 + (size_t)c2 * 1024); \
  } } while (0)

__launch_bounds__(512, 2)
__global__ void carp_gemm2(const unsigned short* __restrict__ h1_pk, const unsigned short* __restrict__ WabT_pk,
                           const float* __restrict__ ba, const float* __restrict__ bb,
                           const float* __restrict__ Wc, float* __restrict__ A_part) {
  __shared__ __align__(16) unsigned short lds[65536];   // 128KB: A [0,64K), B [64K,128K)
  int bid0 = blockIdx.x;
  int bid = (bid0 & 7) * 128 + (bid0 >> 3);
  int bn = bid & 1, bm = bid >> 1;
  int tid = threadIdx.x, lane = tid & 63, wid = tid >> 6;
  int wr = wid >> 1, wc = wid & 1;

  f32x4 acc[4][8] = {};

  G2_STAGE(0, 0, 0); G2_STAGE(1, 1, 0);   // 8/wave outstanding

#pragma unroll 1
  for (int kt = 0; kt < 8; ++kt) {
    int cur = kt & 1, nxt = cur ^ 1;
    if (kt < 7) { G2_STAGE(2 * kt + 2, 0, nxt); G2_STAGE(2 * kt + 3, 1, nxt); }
    if (kt < 7) { WAITVM(8); } else { WAITVM(0); }   // pair kt landed
    BARRIER();
#pragma unroll
    for (int tt = 0; tt < 2; ++tt) {
      const char* Ab = (const char*)lds + cur * 32768 + tt * 16384;
      const char* Bb = (const char*)lds + 65536 + cur * 32768 + tt * 16384 + wc * 8192;
      bf16x8 afr[4], bfr[8];
#pragma unroll
      for (int m = 0; m < 4; ++m)
        afr[m] = *(const bf16x8*)(Ab + (size_t)((wr * 4 + m) * 64 + lane) * 16);
#pragma unroll
      for (int n = 0; n < 8; ++n)
        bfr[n] = *(const bf16x8*)(Bb + (size_t)(n * 64 + lane) * 16);
#pragma unroll
      for (int m = 0; m < 4; ++m)
#pragma unroll
        for (int n = 0; n < 8; ++n)
          acc[m][n] = __builtin_amdgcn_mfma_f32_16x16x32_bf16(afr[m], bfr[n], acc[m][n], 0, 0, 0);
    }
    WAITLGKM0;
    BARRIER();
  }

  int brow = bm * 256;
  int pn = 2 * bn + wc;
  float rowpart[4][4] = {};
#pragma unroll
  for (int n = 0; n < 4; ++n) {
    int d = pn * 64 + n * 16 + (lane & 15);
    float ba_ = ba[d], bb_ = bb[d], wcd = Wc[d];
#pragma unroll
    for (int m = 0; m < 4; ++m)
#pragma unroll
      for (int j = 0; j < 4; ++j) {
        float va = acc[m][n][j] + ba_;
        float vg = acc[m][n + 4][j] + bb_;
        float a = 2.f * frcp(1.f + fexp2(-2.f * LOG2E * va)) - 1.f;   // tanh
        float g = frcp(1.f + fexp2(-LOG2E * vg));                      // sigmoid
        rowpart[m][j] += a * g * wcd;
      }
  }
#pragma unroll
  for (int m = 0; m < 4; ++m)
#pragma unroll
    for (int j = 0; j < 4; ++j) {
      float t = rowpart[m][j];
      t += __shfl_xor(t, 1, 64);
      t += __shfl_xor(t, 2, 64);
      t += __shfl_xor(t, 4, 64);
      t += __shfl_xor(t, 8, 64);
      rowpart[m][j] = t;
    }
  if ((lane & 15) == 0) {
    int slot = bn * 2 + wc;
#pragma unroll
    for (int m = 0; m < 4; ++m)
#pragma unroll
      for (int j = 0; j < 4; ++j) {
        int row = brow + wr * 64 + m * 16 + (lane >> 4) * 4 + j;
        A_part[(size_t)row * 4 + slot] = rowpart[m][j];
      }
  }
}
#undef G2_STAGE

// ---------------- softmax pass 1: A_raw + per-chunk sum(exp)  (max-free: |A_raw| ~ 0.2)
__global__ void carp_softmax1(const float* __restrict__ A_part, const float* __restrict__ bc,
                              float* __restrict__ A_raw_out, float* __restrict__ partial) {
  __shared__ float red[256];
  int blk = blockIdx.x, tid = threadIdx.x;     // 64 blocks x 2048 rows
  int base = blk * 2048;
  float bcv = bc[0];
  float lsum = 0.f;
  for (int i = tid; i < 2048; i += 256) {
    float4 x = *(const float4*)(A_part + (size_t)(base + i) * 4);
    float s = (x.x + x.y) + (x.z + x.w) + bcv;
    A_raw_out[base + i] = s;
    lsum += fexp(s);
  }
  red[tid] = lsum;
  for (int s = 128; s > 0; s >>= 1) { __syncthreads(); if (tid < s) red[tid] += red[tid + s]; }
  if (tid == 0) partial[blk] = red[0];
}

// ---------------- softmax pass 2: per-bag inverse sum (deterministic fixed order)
__global__ void carp_softmax2(const float* __restrict__ partial, float* __restrict__ binv) {
  int b = threadIdx.x;   // 16 threads
  if (b < 16) {
    float s = partial[b * 4] + partial[b * 4 + 1] + partial[b * 4 + 2] + partial[b * 4 + 3];
    binv[b] = 1.f / s;
  }
}

// ---------------- M partials: weight computed inline from A_raw (exp * binv)
__global__ void carp_mkernel(const unsigned short* __restrict__ h1_pk, const float* __restrict__ A_raw,
                             const float* __restrict__ binv, float* __restrict__ Mpart) {
  __shared__ float sw[128];
  int bm = blockIdx.x;
  int tid = threadIdx.x;
  if (tid < 128) sw[tid] = fexp(A_raw[bm * 128 + tid]) * binv[bm >> 6];
  __syncthreads();
  int l = tid & 63;
  float acc[4][8] = {};
#pragma unroll
  for (int tq = 0; tq < 4; ++tq) {
    int tt = (tid >> 6) * 4 + tq;
#pragma unroll
    for (int s = 0; s < 8; ++s) {
      const unsigned short* gp = h1_pk + ((size_t)(bm * 16 + tt) * 512 + s * 64 + l) * 8;
      uint4 raw = *(const uint4*)gp;
      const unsigned short* pv = (const unsigned short*)&raw;
      float w = sw[s * 16 + (l & 15)];
#pragma unroll
      for (int e = 0; e < 8; ++e) acc[tq][e] += w * bf2f(pv[e]);
    }
  }
#pragma unroll
  for (int tq = 0; tq < 4; ++tq)
#pragma unroll
    for (int e = 0; e < 8; ++e) {
      float t = acc[tq][e];
      t += __shfl_xor(t, 1, 64);
      t += __shfl_xor(t, 2, 64);
      t += __shfl_xor(t, 4, 64);
      t += __shfl_xor(t, 8, 64);
      acc[tq][e] = t;
    }
  if ((l & 15) == 0) {
    int cc = (l >> 4) & 3;
#pragma unroll
    for (int tq = 0; tq < 4; ++tq) {
      int tt = (tid >> 6) * 4 + tq;
      float* mp = Mpart + (size_t)bm * 512 + tt * 32 + cc * 8;
#pragma unroll
      for (int e = 0; e < 8; ++e) mp[e] = acc[tq][e];
    }
  }
}

// ---------------- final (unchanged)
__global__ void carp_final(const float* __restrict__ Mpart, const float* __restrict__ Wcls,
                           const float* __restrict__ bcls, float* __restrict__ out) {
  __shared__ float ctx[512];
  int t = threadIdx.x;
  float c = 0.f;
  for (int b = 0; b < 16; ++b) {
    float s = 0.f;
    for (int p = 0; p < 64; ++p) s += Mpart[((size_t)(b * 64 + p) << 9) + t];
    out[131077 + b * 512 + t] = s;
    c += s;
  }
  ctx[t] = c * (1.f / 16.f);
  __syncthreads();
  if (t < 64) {
    float p0 = 0.f, p1 = 0.f;
    for (int hh = t; hh < 512; hh += 64) {
      float cv = ctx[hh];
      p0 += cv * Wcls[hh * 2];
      p1 += cv * Wcls[hh * 2 + 1];
    }
    for (int m = 1; m < 64; m <<= 1) { p0 += __shfl_xor(p0, m, 64); p1 += __shfl_xor(p1, m, 64); }
    if (t == 0) {
      float l0 = p0 + bcls[0], l1 = p1 + bcls[1];
      out[0] = l0; out[1] = l1;
      float mx = fmaxf(l0, l1);
      float e0 = expf(l0 - mx), e1 = expf(l1 - mx);
      float s = e0 + e1;
      out[2] = e0 / s; out[3] = e1 / s;
      out[4] = (l1 > l0) ? 1.0f : 0.0f;
    }
  }
}

extern "C" void kernel_launch(void* const* d_in, const int* in_sizes, int n_in,
                              void* d_out, int out_size, void* d_ws, size_t ws_size,
                              hipStream_t stream) {
  const float* h    = (const float*)d_in[0];
  const float* W1   = (const float*)d_in[1];
  const float* b1   = (const float*)d_in[2];
  const float* Wa   = (const float*)d_in[3];
  const float* ba   = (const float*)d_in[4];
  const float* Wb   = (const float*)d_in[5];
  const float* bb   = (const float*)d_in[6];
  const float* Wc   = (const float*)d_in[7];
  const float* bc   = (const float*)d_in[8];
  const float* Wcls = (const float*)d_in[9];
  const float* bcls = (const float*)d_in[10];
  float* out = (float*)d_out;

  char* ws = (char*)d_ws;
  unsigned short* h1_pk   = (unsigned short*)(ws);                  // 134,217,728 B
  unsigned short* W1T_pk  = (unsigned short*)(ws + 134217728);      //     524,288 B
  unsigned short* WabT_pk = (unsigned short*)(ws + 134742016);      //     524,288 B
  float* A_part           = (float*)(ws + 135266304);               //   2,097,152 B
  float* partial          = (float*)(ws + 139460608);               //         256 B
  float* binv             = (float*)(ws + 139461120);               //          64 B
  float* Mpart            = (float*)(ws + 135266304);               //   overlays A_part (after softmax1)

  carp_wpack   <<<256,  256, 0, stream>>>(W1, Wa, Wb, W1T_pk, WabT_pk);
  carp_gemm1   <<<1024, 512, 0, stream>>>(h, W1T_pk, b1, h1_pk);
  carp_gemm2   <<<1024, 512, 0, stream>>>(h1_pk, WabT_pk, ba, bb, Wc, A_part);
  carp_softmax1<<<64,   256, 0, stream>>>(A_part, bc, out + 5, partial);
  carp_softmax2<<<1,    64,  0, stream>>>(partial, binv);
  carp_mkernel <<<1024, 256, 0, stream>>>(h1_pk, out + 5, binv, Mpart);
  carp_final   <<<1,    512, 0, stream>>>(Mpart, Wcls, bcls, out);
}